// Round 3
// baseline (1022.386 us; speedup 1.0000x reference)
//
#include <hip/hip_runtime.h>
#include <hip/hip_bf16.h>

// ---------------------------------------------------------------------------
// BotGraphSAGE round 6:
//  - f1a + gemm_sage_b: DROP LDS staging entirely. Node-per-lane with k
//    wave-uniform -> each lane float4-reads its OWN row directly (64 lines /
//    instr, fully consumed across 4 consecutive iters via L1/L2), weights
//    stay wave-uniform s_loads. No barriers, no LDS; latency hidden by ILP
//    (#pragma unroll 8 -> 8 independent loads in flight / wave).
//    Round-4 lesson: manual LDS double-buffer fails (compiler sinks loads,
//    VGPR blowup). This removes the need for staging instead.
//  - f1a split-K back to x4 (partials 25.6 MB, 4 slabs; f1c sums 4).
//  - Feature-major GEMM chain + fused head retained from round 5.
// ---------------------------------------------------------------------------

#define BK_SHIFT 8
#define BK_SIZE 256

__global__ void hist_kernel(const int* __restrict__ dst, int* __restrict__ cnt, int E) {
    int e = blockIdx.x * 256 + threadIdx.x;
    if (e < E) atomicAdd(&cnt[dst[e]], 1);
}

// ---- multi-block exclusive scan over cnt[N] -> off[N+1], invc[N] ----
__global__ void scan_reduce_kernel(const int* __restrict__ cnt, int* __restrict__ bsum, int n) {
    int t = threadIdx.x;
    int i = blockIdx.x * 256 + t;
    int v = (i < n) ? cnt[i] : 0;
#pragma unroll
    for (int s = 32; s > 0; s >>= 1) v += __shfl_down(v, s, 64);
    __shared__ int ws[4];
    if ((t & 63) == 0) ws[t >> 6] = v;
    __syncthreads();
    if (t == 0) bsum[blockIdx.x] = ws[0] + ws[1] + ws[2] + ws[3];
}

__global__ void scan_mid_kernel(const int* __restrict__ bsum, int* __restrict__ bbase, int nb) {
    __shared__ int sd[256];
    __shared__ int carry;
    int t = threadIdx.x;
    if (t == 0) carry = 0;
    __syncthreads();
    for (int base = 0; base < nb; base += 256) {
        int v = (base + t < nb) ? bsum[base + t] : 0;
        sd[t] = v;
        __syncthreads();
        for (int d = 1; d < 256; d <<= 1) {
            int x = (t >= d) ? sd[t - d] : 0;
            __syncthreads();
            sd[t] += x;
            __syncthreads();
        }
        if (base + t < nb) bbase[base + t] = carry + sd[t] - v;
        __syncthreads();
        if (t == 0) carry += sd[255];
        __syncthreads();
    }
}

__global__ void scan_final_kernel(const int* __restrict__ cnt, const int* __restrict__ bbase,
                                  int* __restrict__ off, float* __restrict__ invc, int n) {
    __shared__ int sd[256];
    int t = threadIdx.x;
    int i = blockIdx.x * 256 + t;
    int v = (i < n) ? cnt[i] : 0;
    sd[t] = v;
    __syncthreads();
    for (int d = 1; d < 256; d <<= 1) {
        int x = (t >= d) ? sd[t - d] : 0;
        __syncthreads();
        sd[t] += x;
        __syncthreads();
    }
    if (i < n) {
        off[i + 1] = bbase[blockIdx.x] + sd[t];
        invc[i] = 1.0f / fmaxf((float)v, 1.0f);
    }
    if (i == 0) off[0] = 0;
}

__global__ void init_gcur_kernel(const int* __restrict__ off, int* __restrict__ gcur, int nb, int n) {
    int b = blockIdx.x * 256 + threadIdx.x;
    if (b < nb) gcur[b] = off[b * BK_SIZE];
}

// ---- phase A: bin edges into buckets of BK_SIZE dst nodes ----
__global__ __launch_bounds__(256) void bucketA_kernel(const int* __restrict__ src,
    const int* __restrict__ dst, int* __restrict__ gcur,
    uint2* __restrict__ pairs, int E, int nb)
{
    __shared__ int lcnt[256];
    __shared__ int lbase[256];
    int t = threadIdx.x;
    int cbase = blockIdx.x * 4096;
    lcnt[t] = 0;
    __syncthreads();
#pragma unroll
    for (int r = 0; r < 16; ++r) {
        int e = cbase + r * 256 + t;
        if (e < E) atomicAdd(&lcnt[dst[e] >> BK_SHIFT], 1);
    }
    __syncthreads();
    if (t < nb && lcnt[t] > 0) lbase[t] = atomicAdd(&gcur[t], lcnt[t]);
    lcnt[t] = 0;
    __syncthreads();
#pragma unroll
    for (int r = 0; r < 16; ++r) {
        int e = cbase + r * 256 + t;
        if (e < E) {
            int d = dst[e];
            int bk = d >> BK_SHIFT;
            int pos = lbase[bk] + atomicAdd(&lcnt[bk], 1);
            pairs[pos] = make_uint2((unsigned)src[e], (unsigned)d);
        }
    }
}

// ---- phase B: per-bucket LDS-cursor final placement ----
__global__ __launch_bounds__(256) void bucketB_kernel(const uint2* __restrict__ pairs,
    const int* __restrict__ off, int* __restrict__ csr, int n)
{
    __shared__ int lcur[BK_SIZE];
    int t = threadIdx.x;
    int b = blockIdx.x;
    int d0 = b * BK_SIZE;
    int dlim = min(BK_SIZE, n - d0);
    if (t < dlim) lcur[t] = off[d0 + t];
    __syncthreads();
    int start = off[d0];
    int end = off[min(d0 + BK_SIZE, n)];
    for (int i = start + t; i < end; i += 256) {
        uint2 p = pairs[i];
        int pos = atomicAdd(&lcur[p.y & (BK_SIZE - 1)], 1);
        csr[pos] = (int)p.x;
    }
}

// ---------------------------------------------------------------------------
// f1a: des[N,768] @ W_des[768,32], split-K x4 (192 k each), node-per-lane,
// DIRECT per-lane row reads (no LDS, no barriers). k is wave-uniform ->
// weight rows via s_load. Partials feature-major: part[(split*32+c)*N+node].
// ---------------------------------------------------------------------------
__global__ __launch_bounds__(256) void f1a_kernel(const float* __restrict__ des,
    const float* __restrict__ W, float* __restrict__ part, int n)
{
    int t = threadIdx.x;
    int node = blockIdx.x * 256 + t;
    if (node >= n) return;
    int kb0 = blockIdx.y * 192;
    float acc[32];
#pragma unroll
    for (int c = 0; c < 32; ++c) acc[c] = 0.f;

    const float* dp = des + (size_t)node * 768 + kb0;
    const float* wp = W + (size_t)kb0 * 32;
#pragma unroll 8
    for (int k4 = 0; k4 < 48; ++k4) {
        float xv[4];
        *reinterpret_cast<float4*>(xv) = *reinterpret_cast<const float4*>(dp + k4 * 4);
#pragma unroll
        for (int j = 0; j < 4; ++j) {
            const float* wr = wp + (size_t)(k4 * 4 + j) * 32;   // wave-uniform -> s_load
#pragma unroll
            for (int c = 0; c < 32; ++c) acc[c] = fmaf(xv[j], wr[c], acc[c]);
        }
    }
    float* po = part + (size_t)(blockIdx.y * 32) * n + node;
#pragma unroll
    for (int c = 0; c < 32; ++c) po[(size_t)c * n] = acc[c];   // coalesced
}

// f1c: sum 4 transposed partial slabs + bias + leaky -> X^T rows 0..31 (P0)
__global__ __launch_bounds__(256) void f1c_kernel(const float* __restrict__ part,
    const float* __restrict__ b, float* __restrict__ XT, int n)
{
    int node = blockIdx.x * 256 + threadIdx.x;
    if (node >= n) return;
#pragma unroll 8
    for (int c = 0; c < 32; ++c) {
        float v = b[c];
#pragma unroll
        for (int s = 0; s < 4; ++s) v += part[(size_t)(s * 32 + c) * n + node];
        v = v > 0.f ? v : 0.01f * v;
        XT[(size_t)c * n + node] = v;
    }
}

// f1b: num/cat linears -> X^T rows 32..115 (feature-major, coalesced stores)
__global__ __launch_bounds__(256) void f1b_kernel(const float* __restrict__ nump,
    const float* __restrict__ catp,
    const float* __restrict__ Wn, const float* __restrict__ bn,
    const float* __restrict__ Wc, const float* __restrict__ bc,
    float* __restrict__ XT, int n)
{
    int node = blockIdx.x * 256 + threadIdx.x;
    if (node >= n) return;
    float4 nv = *reinterpret_cast<const float4*>(nump + (size_t)node * 4);
    float c0 = catp[(size_t)node * 3];
    float c1 = catp[(size_t)node * 3 + 1];
    float c2 = catp[(size_t)node * 3 + 2];
#pragma unroll 6
    for (int c = 0; c < 42; ++c) {
        float vn = bn[c] + nv.x * Wn[c] + nv.y * Wn[42 + c] + nv.z * Wn[84 + c] + nv.w * Wn[126 + c];
        vn = vn > 0.f ? vn : 0.01f * vn;
        XT[(size_t)(32 + c) * n + node] = vn;
        float vc = bc[c] + c0 * Wc[c] + c1 * Wc[42 + c] + c2 * Wc[84 + c];
        vc = vc > 0.f ? vc : 0.01f * vc;
        XT[(size_t)(74 + c) * n + node] = vc;
    }
}

// ---------------------------------------------------------------------------
// gemm_t: transposed-input node-per-lane GEMM. X is feature-major [K][N]:
// lane load X[k*N+node] is perfectly coalesced -> NO LDS, NO barriers.
// 8 column splits of 16 (grid (nbn,8)).
// MODE 0: WA[K][128] cols cs*16.  MODE 1: cs<4 -> WA[K][64], else WB[K][64].
// ACT: 0 none, 1 relu, 2 leaky.  BIASM: 1 full bias[c0+c]; 2 only cs>=4.
// OUT: 0 transposed dword stores; 1 node-major float4; 3 fused head
//      (leaky(+bias) @ W_o2[128,2] -> atomicAdd, bias2 added by cs==0).
// ---------------------------------------------------------------------------
template<int K, int MODE, int ACT, int BIASM, int OUT>
__global__ __launch_bounds__(256) void gemm_t_kernel(
    const float* __restrict__ X,
    const float* __restrict__ WA, const float* __restrict__ WB,
    const float* __restrict__ bias, const float* __restrict__ bias2,
    float* __restrict__ Y, int n)
{
    int t = threadIdx.x;
    int node = blockIdx.x * 256 + t;
    if (node >= n) return;                     // no barriers -> safe
    int cs = blockIdx.y;
    int c0 = cs * 16;
    float acc[16];
#pragma unroll
    for (int c = 0; c < 16; ++c) acc[c] = 0.f;

    const float* xp = X + node;
    const float* wr0;
    if (MODE == 0)      wr0 = WA + c0;
    else                wr0 = (cs < 4) ? (WA + c0) : (WB + (c0 - 64));
    const int wstride = (MODE == 0) ? 128 : 64;

#pragma unroll 8
    for (int k = 0; k < K; ++k) {
        float x = xp[(size_t)k * n];           // coalesced dword load
        const float* wr = wr0 + (size_t)k * wstride;  // wave-uniform -> s_load
#pragma unroll
        for (int c = 0; c < 16; ++c) acc[c] = fmaf(x, wr[c], acc[c]);
    }

    if (OUT == 3) {
        // fused head: leaky(acc + b_o1) @ W_o2[128,2] partial -> atomicAdd
        float o0 = (cs == 0) ? bias2[0] : 0.f;
        float o1 = (cs == 0) ? bias2[1] : 0.f;
#pragma unroll
        for (int c = 0; c < 16; ++c) {
            float v = acc[c] + bias[c0 + c];
            v = v > 0.f ? v : 0.01f * v;
            o0 = fmaf(v, WB[(c0 + c) * 2],     o0);
            o1 = fmaf(v, WB[(c0 + c) * 2 + 1], o1);
        }
        atomicAdd(&Y[(size_t)node * 2],     o0);
        atomicAdd(&Y[(size_t)node * 2 + 1], o1);
        return;
    }

#pragma unroll
    for (int c = 0; c < 16; ++c) {
        float v = acc[c];
        if (BIASM == 1) v += bias[c0 + c];
        if (BIASM == 2) { if (cs >= 4) v += bias[c0 - 64 + c]; }
        if (ACT == 1) v = fmaxf(v, 0.f);
        else if (ACT == 2) v = v > 0.f ? v : 0.01f * v;
        acc[c] = v;
    }
    if (OUT == 0) {
#pragma unroll
        for (int c = 0; c < 16; ++c)
            Y[(size_t)(c0 + c) * n + node] = acc[c];   // coalesced
    } else {
        float* yp = Y + (size_t)node * 128 + c0;
#pragma unroll
        for (int c4 = 0; c4 < 4; ++c4)
            *reinterpret_cast<float4*>(yp + c4 * 4) =
                make_float4(acc[c4 * 4], acc[c4 * 4 + 1], acc[c4 * 4 + 2], acc[c4 * 4 + 3]);
    }
}

// ---------------------------------------------------------------------------
// gemm_sage_b: node-major input [N,128] (from agg_b), DIRECT per-lane row
// reads (no LDS / barriers; X is L2/L3-resident). K=128 split 64/64 across
// WA/WB. 8 column splits of 16. Output relu(acc+bias), feature-major.
// ---------------------------------------------------------------------------
__global__ __launch_bounds__(256) void gemm_sage_b_kernel(
    const float* __restrict__ X,
    const float* __restrict__ WA, const float* __restrict__ WB,
    const float* __restrict__ bias,
    float* __restrict__ Y, int n)
{
    int t = threadIdx.x;
    int node = blockIdx.x * 256 + t;
    if (node >= n) return;
    int cs = blockIdx.y;
    int c0 = cs * 16;
    float acc[16];
#pragma unroll
    for (int c = 0; c < 16; ++c) acc[c] = 0.f;

    const float* xp = X + (size_t)node * 128;
#pragma unroll 8
    for (int k4 = 0; k4 < 32; ++k4) {
        float xv[4];
        *reinterpret_cast<float4*>(xv) = *reinterpret_cast<const float4*>(xp + k4 * 4);
#pragma unroll
        for (int j = 0; j < 4; ++j) {
            int kk = k4 * 4 + j;
            const float* wr = (kk < 64) ? (WA + (size_t)kk * 128 + c0)
                                        : (WB + (size_t)(kk - 64) * 128 + c0);
#pragma unroll
            for (int c = 0; c < 16; ++c) acc[c] = fmaf(xv[j], wr[c], acc[c]);
        }
    }

#pragma unroll
    for (int c = 0; c < 16; ++c) {
        float v = fmaxf(acc[c] + bias[c0 + c], 0.f);
        Y[(size_t)(c0 + c) * n + node] = v;    // coalesced feature-major
    }
}

// SAGE layer-a epilogue: H[dst] = relu(mean_agg(Y[:,0:64]) + Y[dst,64:128])
__global__ __launch_bounds__(256) void agg_a_kernel(const float* __restrict__ Y,
    const int* __restrict__ off, const int* __restrict__ csr,
    const float* __restrict__ invc, float* __restrict__ H, int n)
{
    int wid = (blockIdx.x * 256 + threadIdx.x) >> 6;
    int f = threadIdx.x & 63;
    if (wid >= n) return;
    float root = Y[(size_t)wid * 128 + 64 + f];
    int b = off[wid], e = off[wid + 1];
    float acc = 0.f;
    for (; b + 8 <= e; b += 8) {
        int idx[8];
#pragma unroll
        for (int j = 0; j < 8; ++j) idx[j] = csr[b + j];
        float v[8];
#pragma unroll
        for (int j = 0; j < 8; ++j) v[j] = Y[(size_t)idx[j] * 128 + f];
#pragma unroll
        for (int j = 0; j < 8; ++j) acc += v[j];
    }
    for (; b + 2 <= e; b += 2) {
        int s0 = csr[b], s1 = csr[b + 1];
        acc += Y[(size_t)s0 * 128 + f] + Y[(size_t)s1 * 128 + f];
    }
    for (; b < e; ++b) acc += Y[(size_t)csr[b] * 128 + f];
    float v = acc * invc[wid] + root;
    H[(size_t)wid * 64 + f] = fmaxf(v, 0.f);
}

// SAGE layer-b pre-GEMM: Z[dst,0:64] = mean_agg(H), Z[dst,64:128] = H[dst]
__global__ __launch_bounds__(256) void agg_b_kernel(const float* __restrict__ H,
    const int* __restrict__ off, const int* __restrict__ csr,
    const float* __restrict__ invc, float* __restrict__ Z, int n)
{
    int wid = (blockIdx.x * 256 + threadIdx.x) >> 6;
    int f = threadIdx.x & 63;
    if (wid >= n) return;
    float root = H[(size_t)wid * 64 + f];
    int b = off[wid], e = off[wid + 1];
    float acc = 0.f;
    for (; b + 8 <= e; b += 8) {
        int idx[8];
#pragma unroll
        for (int j = 0; j < 8; ++j) idx[j] = csr[b + j];
        float v[8];
#pragma unroll
        for (int j = 0; j < 8; ++j) v[j] = H[(size_t)idx[j] * 64 + f];
#pragma unroll
        for (int j = 0; j < 8; ++j) acc += v[j];
    }
    for (; b + 2 <= e; b += 2) {
        int s0 = csr[b], s1 = csr[b + 1];
        acc += H[(size_t)s0 * 64 + f] + H[(size_t)s1 * 64 + f];
    }
    for (; b < e; ++b) acc += H[(size_t)csr[b] * 64 + f];
    Z[(size_t)wid * 128 + f] = acc * invc[wid];
    Z[(size_t)wid * 128 + 64 + f] = root;
}

extern "C" void kernel_launch(void* const* d_in, const int* in_sizes, int n_in,
                              void* d_out, int out_size, void* d_ws, size_t ws_size,
                              hipStream_t stream)
{
    const float* des   = (const float*)d_in[0];
    const float* nump  = (const float*)d_in[2];
    const float* catp  = (const float*)d_in[3];
    const int*   ei    = (const int*)d_in[4];
    const float* W_des = (const float*)d_in[5];  const float* b_des = (const float*)d_in[6];
    const float* W_num = (const float*)d_in[7];  const float* b_num = (const float*)d_in[8];
    const float* W_cat = (const float*)d_in[9];  const float* b_cat = (const float*)d_in[10];
    const float* W_in  = (const float*)d_in[11]; const float* b_in  = (const float*)d_in[12];
    const float* s1a_Wl = (const float*)d_in[13]; const float* s1a_bl = (const float*)d_in[14];
    const float* s1a_Wr = (const float*)d_in[15];
    const float* s1b_Wl = (const float*)d_in[16]; const float* s1b_bl = (const float*)d_in[17];
    const float* s1b_Wr = (const float*)d_in[18];
    const float* s2a_Wl = (const float*)d_in[19]; const float* s2a_bl = (const float*)d_in[20];
    const float* s2a_Wr = (const float*)d_in[21];
    const float* s2b_Wl = (const float*)d_in[22]; const float* s2b_bl = (const float*)d_in[23];
    const float* s2b_Wr = (const float*)d_in[24];
    const float* W_o1  = (const float*)d_in[25]; const float* b_o1 = (const float*)d_in[26];
    const float* W_o2  = (const float*)d_in[27]; const float* b_o2 = (const float*)d_in[28];
    float* out = (float*)d_out;

    int N = in_sizes[0] / 768;
    int E = in_sizes[4] / 2;
    const int* srcp = ei;
    const int* dstp = ei + E;
    int NB = (N + BK_SIZE - 1) >> BK_SHIFT;       // dst buckets
    int NBLK = (N + 255) / 256;                   // scan blocks

    float* P0 = (float*)d_ws;
    float* P1 = P0 + (size_t)128 * N;
    float* P2 = P1 + (size_t)128 * N;   // pairs during CSR
    int* cnt   = (int*)(P2 + (size_t)128 * N);
    int* off   = cnt + N;
    float* invc = (float*)(off + (N + 1));
    int* csr   = (int*)(invc + N);
    int* bsum  = csr + E;
    int* bbase = bsum + NBLK;
    int* gcur  = bbase + NBLK;
    uint2* pairs = (uint2*)P2;

    // --- CSR build ---
    hipMemsetAsync(cnt, 0, (size_t)N * sizeof(int), stream);
    hipMemsetAsync(out, 0, (size_t)N * 2 * sizeof(float), stream);  // fused-head atomics
    hist_kernel<<<(E + 255) / 256, 256, 0, stream>>>(dstp, cnt, E);
    scan_reduce_kernel<<<NBLK, 256, 0, stream>>>(cnt, bsum, N);
    scan_mid_kernel<<<1, 256, 0, stream>>>(bsum, bbase, NBLK);
    scan_final_kernel<<<NBLK, 256, 0, stream>>>(cnt, bbase, off, invc, N);
    init_gcur_kernel<<<(NB + 255) / 256, 256, 0, stream>>>(off, gcur, NB, N);
    bucketA_kernel<<<(E + 4095) / 4096, 256, 0, stream>>>(srcp, dstp, gcur, pairs, E, NB);
    bucketB_kernel<<<NB, 256, 0, stream>>>(pairs, off, csr, N);

    int nbn = (N + 255) / 256;
    dim3 g8(nbn, 8);
    int nbw = (N + 3) / 4;

    // --- Front MLP:  X^T in P0 (rows 0..115) ---
    f1a_kernel<<<dim3(nbn, 4), 256, 0, stream>>>(des, W_des, P1, N);  // 4 slabs in P1
    f1b_kernel<<<nbn, 256, 0, stream>>>(nump, catp, W_num, b_num, W_cat, b_cat, P0, N);
    f1c_kernel<<<nbn, 256, 0, stream>>>(P1, b_des, P0, N);
    gemm_t_kernel<116, 0, 2, 1, 0><<<g8, 256, 0, stream>>>(P0, W_in, nullptr, b_in, nullptr, P1, N);

    // --- SAGE block 1 ---
    gemm_t_kernel<128, 1, 0, 2, 1><<<g8, 256, 0, stream>>>(P1, s1a_Wl, s1a_Wr, s1a_bl, nullptr, P2, N);
    agg_a_kernel<<<nbw, 256, 0, stream>>>(P2, off, csr, invc, P0, N);
    agg_b_kernel<<<nbw, 256, 0, stream>>>(P0, off, csr, invc, P1, N);
    gemm_sage_b_kernel<<<g8, 256, 0, stream>>>(P1, s1b_Wl, s1b_Wr, s1b_bl, P2, N);

    // --- SAGE block 2 ---
    gemm_t_kernel<128, 1, 0, 2, 1><<<g8, 256, 0, stream>>>(P2, s2a_Wl, s2a_Wr, s2a_bl, nullptr, P0, N);
    agg_a_kernel<<<nbw, 256, 0, stream>>>(P0, off, csr, invc, P1, N);
    agg_b_kernel<<<nbw, 256, 0, stream>>>(P1, off, csr, invc, P0, N);
    gemm_sage_b_kernel<<<g8, 256, 0, stream>>>(P0, s2b_Wl, s2b_Wr, s2b_bl, P1, N);

    // --- Head: leaky(X3^T @ W_o1 + b_o1) @ W_o2 + b_o2 (fused, atomics) ---
    gemm_t_kernel<128, 0, 3, 1, 3><<<g8, 256, 0, stream>>>(P1, W_o1, W_o2, b_o1, b_o2, out, N);
}

// Round 4
// 1021.764 us; speedup vs baseline: 1.0006x; 1.0006x over previous
//
#include <hip/hip_runtime.h>
#include <hip/hip_bf16.h>

// ---------------------------------------------------------------------------
// BotGraphSAGE round 7:
//  - REVERT gemm_sage_b to round-5 staged form (round-6 direct reads cost
//    ~+95 us; uncoalesced per-lane rows thrash L1 -- measured twice).
//  - f1a: staged structure (best known) but 128 nodes/block x (node,colhalf)
//    thread map -> LDS 16.5 KB, grid (391,4)=1564 blocks = 6.1 blocks/CU,
//    24 waves/CU (75% occ) vs 31%. Attacks the measured grid-limited
//    occupancy, which is what keeps f1a latency-bound.
//  - agg_a/agg_b: 4-edge x float4 gather (1 KB / instr, 16 rows in flight
//    per wave) + 2-step shfl reduce. Attacks gather latency.
//  - Feature-major GEMM chain, fused head, CSR build unchanged.
// ---------------------------------------------------------------------------

#define BK_SHIFT 8
#define BK_SIZE 256

__device__ __forceinline__ void acc4(float4& a, float4 v) {
    a.x += v.x; a.y += v.y; a.z += v.z; a.w += v.w;
}

__global__ void hist_kernel(const int* __restrict__ dst, int* __restrict__ cnt, int E) {
    int e = blockIdx.x * 256 + threadIdx.x;
    if (e < E) atomicAdd(&cnt[dst[e]], 1);
}

// ---- multi-block exclusive scan over cnt[N] -> off[N+1], invc[N] ----
__global__ void scan_reduce_kernel(const int* __restrict__ cnt, int* __restrict__ bsum, int n) {
    int t = threadIdx.x;
    int i = blockIdx.x * 256 + t;
    int v = (i < n) ? cnt[i] : 0;
#pragma unroll
    for (int s = 32; s > 0; s >>= 1) v += __shfl_down(v, s, 64);
    __shared__ int ws[4];
    if ((t & 63) == 0) ws[t >> 6] = v;
    __syncthreads();
    if (t == 0) bsum[blockIdx.x] = ws[0] + ws[1] + ws[2] + ws[3];
}

__global__ void scan_mid_kernel(const int* __restrict__ bsum, int* __restrict__ bbase, int nb) {
    __shared__ int sd[256];
    __shared__ int carry;
    int t = threadIdx.x;
    if (t == 0) carry = 0;
    __syncthreads();
    for (int base = 0; base < nb; base += 256) {
        int v = (base + t < nb) ? bsum[base + t] : 0;
        sd[t] = v;
        __syncthreads();
        for (int d = 1; d < 256; d <<= 1) {
            int x = (t >= d) ? sd[t - d] : 0;
            __syncthreads();
            sd[t] += x;
            __syncthreads();
        }
        if (base + t < nb) bbase[base + t] = carry + sd[t] - v;
        __syncthreads();
        if (t == 0) carry += sd[255];
        __syncthreads();
    }
}

__global__ void scan_final_kernel(const int* __restrict__ cnt, const int* __restrict__ bbase,
                                  int* __restrict__ off, float* __restrict__ invc, int n) {
    __shared__ int sd[256];
    int t = threadIdx.x;
    int i = blockIdx.x * 256 + t;
    int v = (i < n) ? cnt[i] : 0;
    sd[t] = v;
    __syncthreads();
    for (int d = 1; d < 256; d <<= 1) {
        int x = (t >= d) ? sd[t - d] : 0;
        __syncthreads();
        sd[t] += x;
        __syncthreads();
    }
    if (i < n) {
        off[i + 1] = bbase[blockIdx.x] + sd[t];
        invc[i] = 1.0f / fmaxf((float)v, 1.0f);
    }
    if (i == 0) off[0] = 0;
}

__global__ void init_gcur_kernel(const int* __restrict__ off, int* __restrict__ gcur, int nb, int n) {
    int b = blockIdx.x * 256 + threadIdx.x;
    if (b < nb) gcur[b] = off[b * BK_SIZE];
}

// ---- phase A: bin edges into buckets of BK_SIZE dst nodes ----
__global__ __launch_bounds__(256) void bucketA_kernel(const int* __restrict__ src,
    const int* __restrict__ dst, int* __restrict__ gcur,
    uint2* __restrict__ pairs, int E, int nb)
{
    __shared__ int lcnt[256];
    __shared__ int lbase[256];
    int t = threadIdx.x;
    int cbase = blockIdx.x * 4096;
    lcnt[t] = 0;
    __syncthreads();
#pragma unroll
    for (int r = 0; r < 16; ++r) {
        int e = cbase + r * 256 + t;
        if (e < E) atomicAdd(&lcnt[dst[e] >> BK_SHIFT], 1);
    }
    __syncthreads();
    if (t < nb && lcnt[t] > 0) lbase[t] = atomicAdd(&gcur[t], lcnt[t]);
    lcnt[t] = 0;
    __syncthreads();
#pragma unroll
    for (int r = 0; r < 16; ++r) {
        int e = cbase + r * 256 + t;
        if (e < E) {
            int d = dst[e];
            int bk = d >> BK_SHIFT;
            int pos = lbase[bk] + atomicAdd(&lcnt[bk], 1);
            pairs[pos] = make_uint2((unsigned)src[e], (unsigned)d);
        }
    }
}

// ---- phase B: per-bucket LDS-cursor final placement ----
__global__ __launch_bounds__(256) void bucketB_kernel(const uint2* __restrict__ pairs,
    const int* __restrict__ off, int* __restrict__ csr, int n)
{
    __shared__ int lcur[BK_SIZE];
    int t = threadIdx.x;
    int b = blockIdx.x;
    int d0 = b * BK_SIZE;
    int dlim = min(BK_SIZE, n - d0);
    if (t < dlim) lcur[t] = off[d0 + t];
    __syncthreads();
    int start = off[d0];
    int end = off[min(d0 + BK_SIZE, n)];
    for (int i = start + t; i < end; i += 256) {
        uint2 p = pairs[i];
        int pos = atomicAdd(&lcur[p.y & (BK_SIZE - 1)], 1);
        csr[pos] = (int)p.x;
    }
}

// ---------------------------------------------------------------------------
// f1a: des[N,768] @ W_des[768,32], split-K x4 (192 k each).
// 128 nodes/block, 256 threads = (node 0..127) x (col-half 0..1), staged
// 32-k chunks in LDS (16.5 KB -> 6 blocks/CU from grid 1564, 24 waves/CU).
// Partials feature-major: part[(split*32 + chalf*16 + c)*N + node].
// ---------------------------------------------------------------------------
__global__ __launch_bounds__(256) void f1a_kernel(const float* __restrict__ des,
    const float* __restrict__ W, float* __restrict__ part, int n)
{
    __shared__ float sX[32 * 129];
    int t = threadIdx.x;
    int nbase = blockIdx.x * 128;
    int nl = t & 127;            // node within block
    int chalf = t >> 7;          // 0/1 -> cols 0..15 / 16..31 (wave-uniform)
    int node = nbase + nl;
    int kb0 = blockIdx.y * 192;
    int c0 = chalf * 16;
    float acc[16];
#pragma unroll
    for (int c = 0; c < 16; ++c) acc[c] = 0.f;

    for (int kc = 0; kc < 192; kc += 32) {
        __syncthreads();
#pragma unroll
        for (int r = 0; r < 4; ++r) {
            int i = r * 256 + t;          // 0..1023 float4 slots
            int k4 = i & 7, nn = i >> 3;  // 8 float4 along k, 128 nodes
            int gn = nbase + nn;
            float4 v = make_float4(0.f, 0.f, 0.f, 0.f);
            if (gn < n)
                v = *reinterpret_cast<const float4*>(des + (size_t)gn * 768 + kb0 + kc + k4 * 4);
            sX[(k4 * 4 + 0) * 129 + nn] = v.x;
            sX[(k4 * 4 + 1) * 129 + nn] = v.y;
            sX[(k4 * 4 + 2) * 129 + nn] = v.z;
            sX[(k4 * 4 + 3) * 129 + nn] = v.w;
        }
        __syncthreads();
        const float* wbase = W + (size_t)(kb0 + kc) * 32 + c0;
#pragma unroll 8
        for (int k = 0; k < 32; ++k) {
            float x = sX[k * 129 + nl];
            const float* wr = wbase + k * 32;   // wave-uniform -> s_load
#pragma unroll
            for (int c = 0; c < 16; ++c) acc[c] = fmaf(x, wr[c], acc[c]);
        }
    }
    if (node < n) {
        float* po = part + (size_t)(blockIdx.y * 32 + c0) * n + node;
#pragma unroll
        for (int c = 0; c < 16; ++c) po[(size_t)c * n] = acc[c];   // coalesced
    }
}

// f1c: sum 4 transposed partial slabs + bias + leaky -> X^T rows 0..31 (P0)
__global__ __launch_bounds__(256) void f1c_kernel(const float* __restrict__ part,
    const float* __restrict__ b, float* __restrict__ XT, int n)
{
    int node = blockIdx.x * 256 + threadIdx.x;
    if (node >= n) return;
#pragma unroll 8
    for (int c = 0; c < 32; ++c) {
        float v = b[c];
#pragma unroll
        for (int s = 0; s < 4; ++s) v += part[(size_t)(s * 32 + c) * n + node];
        v = v > 0.f ? v : 0.01f * v;
        XT[(size_t)c * n + node] = v;
    }
}

// f1b: num/cat linears -> X^T rows 32..115 (feature-major, coalesced stores)
__global__ __launch_bounds__(256) void f1b_kernel(const float* __restrict__ nump,
    const float* __restrict__ catp,
    const float* __restrict__ Wn, const float* __restrict__ bn,
    const float* __restrict__ Wc, const float* __restrict__ bc,
    float* __restrict__ XT, int n)
{
    int node = blockIdx.x * 256 + threadIdx.x;
    if (node >= n) return;
    float4 nv = *reinterpret_cast<const float4*>(nump + (size_t)node * 4);
    float c0 = catp[(size_t)node * 3];
    float c1 = catp[(size_t)node * 3 + 1];
    float c2 = catp[(size_t)node * 3 + 2];
#pragma unroll 6
    for (int c = 0; c < 42; ++c) {
        float vn = bn[c] + nv.x * Wn[c] + nv.y * Wn[42 + c] + nv.z * Wn[84 + c] + nv.w * Wn[126 + c];
        vn = vn > 0.f ? vn : 0.01f * vn;
        XT[(size_t)(32 + c) * n + node] = vn;
        float vc = bc[c] + c0 * Wc[c] + c1 * Wc[42 + c] + c2 * Wc[84 + c];
        vc = vc > 0.f ? vc : 0.01f * vc;
        XT[(size_t)(74 + c) * n + node] = vc;
    }
}

// ---------------------------------------------------------------------------
// gemm_t: transposed-input node-per-lane GEMM. X is feature-major [K][N]:
// lane load X[k*N+node] is perfectly coalesced -> NO LDS, NO barriers.
// 8 column splits of 16 (grid (nbn,8)).
// MODE 0: WA[K][128] cols cs*16.  MODE 1: cs<4 -> WA[K][64], else WB[K][64].
// ACT: 0 none, 1 relu, 2 leaky.  BIASM: 1 full bias[c0+c]; 2 only cs>=4.
// OUT: 0 transposed dword stores; 1 node-major float4; 3 fused head
//      (leaky(+bias) @ W_o2[128,2] -> atomicAdd, bias2 added by cs==0).
// ---------------------------------------------------------------------------
template<int K, int MODE, int ACT, int BIASM, int OUT>
__global__ __launch_bounds__(256) void gemm_t_kernel(
    const float* __restrict__ X,
    const float* __restrict__ WA, const float* __restrict__ WB,
    const float* __restrict__ bias, const float* __restrict__ bias2,
    float* __restrict__ Y, int n)
{
    int t = threadIdx.x;
    int node = blockIdx.x * 256 + t;
    if (node >= n) return;                     // no barriers -> safe
    int cs = blockIdx.y;
    int c0 = cs * 16;
    float acc[16];
#pragma unroll
    for (int c = 0; c < 16; ++c) acc[c] = 0.f;

    const float* xp = X + node;
    const float* wr0;
    if (MODE == 0)      wr0 = WA + c0;
    else                wr0 = (cs < 4) ? (WA + c0) : (WB + (c0 - 64));
    const int wstride = (MODE == 0) ? 128 : 64;

#pragma unroll 8
    for (int k = 0; k < K; ++k) {
        float x = xp[(size_t)k * n];           // coalesced dword load
        const float* wr = wr0 + (size_t)k * wstride;  // wave-uniform -> s_load
#pragma unroll
        for (int c = 0; c < 16; ++c) acc[c] = fmaf(x, wr[c], acc[c]);
    }

    if (OUT == 3) {
        // fused head: leaky(acc + b_o1) @ W_o2[128,2] partial -> atomicAdd
        float o0 = (cs == 0) ? bias2[0] : 0.f;
        float o1 = (cs == 0) ? bias2[1] : 0.f;
#pragma unroll
        for (int c = 0; c < 16; ++c) {
            float v = acc[c] + bias[c0 + c];
            v = v > 0.f ? v : 0.01f * v;
            o0 = fmaf(v, WB[(c0 + c) * 2],     o0);
            o1 = fmaf(v, WB[(c0 + c) * 2 + 1], o1);
        }
        atomicAdd(&Y[(size_t)node * 2],     o0);
        atomicAdd(&Y[(size_t)node * 2 + 1], o1);
        return;
    }

#pragma unroll
    for (int c = 0; c < 16; ++c) {
        float v = acc[c];
        if (BIASM == 1) v += bias[c0 + c];
        if (BIASM == 2) { if (cs >= 4) v += bias[c0 - 64 + c]; }
        if (ACT == 1) v = fmaxf(v, 0.f);
        else if (ACT == 2) v = v > 0.f ? v : 0.01f * v;
        acc[c] = v;
    }
    if (OUT == 0) {
#pragma unroll
        for (int c = 0; c < 16; ++c)
            Y[(size_t)(c0 + c) * n + node] = acc[c];   // coalesced
    } else {
        float* yp = Y + (size_t)node * 128 + c0;
#pragma unroll
        for (int c4 = 0; c4 < 4; ++c4)
            *reinterpret_cast<float4*>(yp + c4 * 4) =
                make_float4(acc[c4 * 4], acc[c4 * 4 + 1], acc[c4 * 4 + 2], acc[c4 * 4 + 3]);
    }
}

// ---------------------------------------------------------------------------
// gemm_sage_b: node-major input [N,128] (from agg_b), staged (round-5 form).
// K=128 split 64/64 across WA[64][128]/WB[64][128]. 8 column splits of 16,
// 16-k chunks (LDS 16.5 KB, stride 258). Output relu, feature-major stores.
// ---------------------------------------------------------------------------
__global__ __launch_bounds__(256) void gemm_sage_b_kernel(
    const float* __restrict__ X,
    const float* __restrict__ WA, const float* __restrict__ WB,
    const float* __restrict__ bias,
    float* __restrict__ Y, int n)
{
    __shared__ float sX[16 * 258];
    int t = threadIdx.x;
    int nbase = blockIdx.x * 256;
    int node = nbase + t;
    int cs = blockIdx.y;
    int c0 = cs * 16;
    float acc[16];
#pragma unroll
    for (int c = 0; c < 16; ++c) acc[c] = 0.f;

    for (int ch = 0; ch < 8; ++ch) {
        int kb = ch * 16;
        __syncthreads();
#pragma unroll
        for (int r = 0; r < 4; ++r) {
            int i = r * 256 + t;
            int k4 = i & 3, nn = i >> 2;
            int gn = nbase + nn;
            float4 v = make_float4(0.f, 0.f, 0.f, 0.f);
            if (gn < n)
                v = *reinterpret_cast<const float4*>(X + (size_t)gn * 128 + kb + k4 * 4);
            sX[(k4 * 4 + 0) * 258 + nn] = v.x;
            sX[(k4 * 4 + 1) * 258 + nn] = v.y;
            sX[(k4 * 4 + 2) * 258 + nn] = v.z;
            sX[(k4 * 4 + 3) * 258 + nn] = v.w;
        }
        __syncthreads();
#pragma unroll 4
        for (int k = 0; k < 16; ++k) {
            float x = sX[k * 258 + t];
            int kk = kb + k;
            const float* wr = (kk < 64) ? (WA + (size_t)kk * 128 + c0)
                                        : (WB + (size_t)(kk - 64) * 128 + c0);
#pragma unroll
            for (int c = 0; c < 16; ++c) acc[c] = fmaf(x, wr[c], acc[c]);
        }
    }

    if (node >= n) return;
#pragma unroll
    for (int c = 0; c < 16; ++c) {
        float v = fmaxf(acc[c] + bias[c0 + c], 0.f);
        Y[(size_t)(c0 + c) * n + node] = v;    // coalesced feature-major
    }
}

// ---------------------------------------------------------------------------
// agg_a: H[dst] = relu(mean_agg(Y[:,0:64]) + Y[dst,64:128]).
// Wave per node; lane = (edge slot e4 = l>>4) x (feature quad fq = l&15).
// Each gather instr: 4 rows x 256 B = 1 KB; 4-group batch -> 16 rows in
// flight. 2-step shfl reduce across e4; lanes 0..15 write float4.
// ---------------------------------------------------------------------------
__global__ __launch_bounds__(256) void agg_a_kernel(const float* __restrict__ Y,
    const int* __restrict__ off, const int* __restrict__ csr,
    const float* __restrict__ invc, float* __restrict__ H, int n)
{
    int wid = (blockIdx.x * 256 + threadIdx.x) >> 6;
    int l = threadIdx.x & 63;
    if (wid >= n) return;
    int e4 = l >> 4, fq = l & 15;
    int b = off[wid], e = off[wid + 1];
    int deg = e - b;
    int nfull = deg >> 2;           // 4-edge groups
    float4 acc = make_float4(0.f, 0.f, 0.f, 0.f);
    int i = b + e4;
    int g = 0;
    for (; g + 4 <= nfull; g += 4, i += 16) {
        int i0 = csr[i], i1 = csr[i + 4], i2 = csr[i + 8], i3 = csr[i + 12];
        float4 v0 = *reinterpret_cast<const float4*>(Y + (size_t)i0 * 128 + fq * 4);
        float4 v1 = *reinterpret_cast<const float4*>(Y + (size_t)i1 * 128 + fq * 4);
        float4 v2 = *reinterpret_cast<const float4*>(Y + (size_t)i2 * 128 + fq * 4);
        float4 v3 = *reinterpret_cast<const float4*>(Y + (size_t)i3 * 128 + fq * 4);
        acc4(acc, v0); acc4(acc, v1); acc4(acc, v2); acc4(acc, v3);
    }
    for (; g < nfull; ++g, i += 4) {
        int i0 = csr[i];
        acc4(acc, *reinterpret_cast<const float4*>(Y + (size_t)i0 * 128 + fq * 4));
    }
    int rem = deg & 3;
    if (e4 < rem) {
        int i0 = csr[b + (nfull << 2) + e4];
        acc4(acc, *reinterpret_cast<const float4*>(Y + (size_t)i0 * 128 + fq * 4));
    }
    // reduce across e4 groups (lanes l, l+16, l+32, l+48 -> lane l<16)
    acc.x += __shfl_down(acc.x, 32, 64); acc.y += __shfl_down(acc.y, 32, 64);
    acc.z += __shfl_down(acc.z, 32, 64); acc.w += __shfl_down(acc.w, 32, 64);
    acc.x += __shfl_down(acc.x, 16, 64); acc.y += __shfl_down(acc.y, 16, 64);
    acc.z += __shfl_down(acc.z, 16, 64); acc.w += __shfl_down(acc.w, 16, 64);
    if (e4 == 0) {
        float ic = invc[wid];
        float4 root = *reinterpret_cast<const float4*>(Y + (size_t)wid * 128 + 64 + fq * 4);
        float4 o;
        o.x = fmaxf(acc.x * ic + root.x, 0.f);
        o.y = fmaxf(acc.y * ic + root.y, 0.f);
        o.z = fmaxf(acc.z * ic + root.z, 0.f);
        o.w = fmaxf(acc.w * ic + root.w, 0.f);
        *reinterpret_cast<float4*>(H + (size_t)wid * 64 + fq * 4) = o;
    }
}

// agg_b: Z[dst,0:64] = mean_agg(H), Z[dst,64:128] = H[dst]. Same scheme,
// H rows are 64 floats.
__global__ __launch_bounds__(256) void agg_b_kernel(const float* __restrict__ H,
    const int* __restrict__ off, const int* __restrict__ csr,
    const float* __restrict__ invc, float* __restrict__ Z, int n)
{
    int wid = (blockIdx.x * 256 + threadIdx.x) >> 6;
    int l = threadIdx.x & 63;
    if (wid >= n) return;
    int e4 = l >> 4, fq = l & 15;
    int b = off[wid], e = off[wid + 1];
    int deg = e - b;
    int nfull = deg >> 2;
    float4 acc = make_float4(0.f, 0.f, 0.f, 0.f);
    int i = b + e4;
    int g = 0;
    for (; g + 4 <= nfull; g += 4, i += 16) {
        int i0 = csr[i], i1 = csr[i + 4], i2 = csr[i + 8], i3 = csr[i + 12];
        float4 v0 = *reinterpret_cast<const float4*>(H + (size_t)i0 * 64 + fq * 4);
        float4 v1 = *reinterpret_cast<const float4*>(H + (size_t)i1 * 64 + fq * 4);
        float4 v2 = *reinterpret_cast<const float4*>(H + (size_t)i2 * 64 + fq * 4);
        float4 v3 = *reinterpret_cast<const float4*>(H + (size_t)i3 * 64 + fq * 4);
        acc4(acc, v0); acc4(acc, v1); acc4(acc, v2); acc4(acc, v3);
    }
    for (; g < nfull; ++g, i += 4) {
        int i0 = csr[i];
        acc4(acc, *reinterpret_cast<const float4*>(H + (size_t)i0 * 64 + fq * 4));
    }
    int rem = deg & 3;
    if (e4 < rem) {
        int i0 = csr[b + (nfull << 2) + e4];
        acc4(acc, *reinterpret_cast<const float4*>(H + (size_t)i0 * 64 + fq * 4));
    }
    acc.x += __shfl_down(acc.x, 32, 64); acc.y += __shfl_down(acc.y, 32, 64);
    acc.z += __shfl_down(acc.z, 32, 64); acc.w += __shfl_down(acc.w, 32, 64);
    acc.x += __shfl_down(acc.x, 16, 64); acc.y += __shfl_down(acc.y, 16, 64);
    acc.z += __shfl_down(acc.z, 16, 64); acc.w += __shfl_down(acc.w, 16, 64);
    if (e4 == 0) {
        float ic = invc[wid];
        float4 root = *reinterpret_cast<const float4*>(H + (size_t)wid * 64 + fq * 4);
        float4 m;
        m.x = acc.x * ic; m.y = acc.y * ic; m.z = acc.z * ic; m.w = acc.w * ic;
        *reinterpret_cast<float4*>(Z + (size_t)wid * 128 + fq * 4) = m;
        *reinterpret_cast<float4*>(Z + (size_t)wid * 128 + 64 + fq * 4) = root;
    }
}

extern "C" void kernel_launch(void* const* d_in, const int* in_sizes, int n_in,
                              void* d_out, int out_size, void* d_ws, size_t ws_size,
                              hipStream_t stream)
{
    const float* des   = (const float*)d_in[0];
    const float* nump  = (const float*)d_in[2];
    const float* catp  = (const float*)d_in[3];
    const int*   ei    = (const int*)d_in[4];
    const float* W_des = (const float*)d_in[5];  const float* b_des = (const float*)d_in[6];
    const float* W_num = (const float*)d_in[7];  const float* b_num = (const float*)d_in[8];
    const float* W_cat = (const float*)d_in[9];  const float* b_cat = (const float*)d_in[10];
    const float* W_in  = (const float*)d_in[11]; const float* b_in  = (const float*)d_in[12];
    const float* s1a_Wl = (const float*)d_in[13]; const float* s1a_bl = (const float*)d_in[14];
    const float* s1a_Wr = (const float*)d_in[15];
    const float* s1b_Wl = (const float*)d_in[16]; const float* s1b_bl = (const float*)d_in[17];
    const float* s1b_Wr = (const float*)d_in[18];
    const float* s2a_Wl = (const float*)d_in[19]; const float* s2a_bl = (const float*)d_in[20];
    const float* s2a_Wr = (const float*)d_in[21];
    const float* s2b_Wl = (const float*)d_in[22]; const float* s2b_bl = (const float*)d_in[23];
    const float* s2b_Wr = (const float*)d_in[24];
    const float* W_o1  = (const float*)d_in[25]; const float* b_o1 = (const float*)d_in[26];
    const float* W_o2  = (const float*)d_in[27]; const float* b_o2 = (const float*)d_in[28];
    float* out = (float*)d_out;

    int N = in_sizes[0] / 768;
    int E = in_sizes[4] / 2;
    const int* srcp = ei;
    const int* dstp = ei + E;
    int NB = (N + BK_SIZE - 1) >> BK_SHIFT;       // dst buckets
    int NBLK = (N + 255) / 256;                   // scan blocks

    float* P0 = (float*)d_ws;
    float* P1 = P0 + (size_t)128 * N;
    float* P2 = P1 + (size_t)128 * N;   // pairs during CSR
    int* cnt   = (int*)(P2 + (size_t)128 * N);
    int* off   = cnt + N;
    float* invc = (float*)(off + (N + 1));
    int* csr   = (int*)(invc + N);
    int* bsum  = csr + E;
    int* bbase = bsum + NBLK;
    int* gcur  = bbase + NBLK;
    uint2* pairs = (uint2*)P2;

    // --- CSR build ---
    hipMemsetAsync(cnt, 0, (size_t)N * sizeof(int), stream);
    hipMemsetAsync(out, 0, (size_t)N * 2 * sizeof(float), stream);  // fused-head atomics
    hist_kernel<<<(E + 255) / 256, 256, 0, stream>>>(dstp, cnt, E);
    scan_reduce_kernel<<<NBLK, 256, 0, stream>>>(cnt, bsum, N);
    scan_mid_kernel<<<1, 256, 0, stream>>>(bsum, bbase, NBLK);
    scan_final_kernel<<<NBLK, 256, 0, stream>>>(cnt, bbase, off, invc, N);
    init_gcur_kernel<<<(NB + 255) / 256, 256, 0, stream>>>(off, gcur, NB, N);
    bucketA_kernel<<<(E + 4095) / 4096, 256, 0, stream>>>(srcp, dstp, gcur, pairs, E, NB);
    bucketB_kernel<<<NB, 256, 0, stream>>>(pairs, off, csr, N);

    int nbn = (N + 255) / 256;
    int nbn128 = (N + 127) / 128;
    dim3 g8(nbn, 8);
    int nbw = (N + 3) / 4;

    // --- Front MLP:  X^T in P0 (rows 0..115) ---
    f1a_kernel<<<dim3(nbn128, 4), 256, 0, stream>>>(des, W_des, P1, N);  // 4 slabs in P1
    f1b_kernel<<<nbn, 256, 0, stream>>>(nump, catp, W_num, b_num, W_cat, b_cat, P0, N);
    f1c_kernel<<<nbn, 256, 0, stream>>>(P1, b_des, P0, N);
    gemm_t_kernel<116, 0, 2, 1, 0><<<g8, 256, 0, stream>>>(P0, W_in, nullptr, b_in, nullptr, P1, N);

    // --- SAGE block 1 ---
    gemm_t_kernel<128, 1, 0, 2, 1><<<g8, 256, 0, stream>>>(P1, s1a_Wl, s1a_Wr, s1a_bl, nullptr, P2, N);
    agg_a_kernel<<<nbw, 256, 0, stream>>>(P2, off, csr, invc, P0, N);
    agg_b_kernel<<<nbw, 256, 0, stream>>>(P0, off, csr, invc, P1, N);
    gemm_sage_b_kernel<<<g8, 256, 0, stream>>>(P1, s1b_Wl, s1b_Wr, s1b_bl, P2, N);

    // --- SAGE block 2 ---
    gemm_t_kernel<128, 1, 0, 2, 1><<<g8, 256, 0, stream>>>(P2, s2a_Wl, s2a_Wr, s2a_bl, nullptr, P0, N);
    agg_a_kernel<<<nbw, 256, 0, stream>>>(P0, off, csr, invc, P1, N);
    agg_b_kernel<<<nbw, 256, 0, stream>>>(P1, off, csr, invc, P0, N);
    gemm_sage_b_kernel<<<g8, 256, 0, stream>>>(P0, s2b_Wl, s2b_Wr, s2b_bl, P1, N);

    // --- Head: leaky(X3^T @ W_o1 + b_o1) @ W_o2 + b_o2 (fused, atomics) ---
    gemm_t_kernel<128, 0, 3, 1, 3><<<g8, 256, 0, stream>>>(P1, W_o1, W_o2, b_o1, b_o2, out, N);
}

// Round 5
// 896.660 us; speedup vs baseline: 1.1402x; 1.1395x over previous
//
#include <hip/hip_runtime.h>
#include <hip/hip_bf16.h>

// ---------------------------------------------------------------------------
// BotGraphSAGE round 8:
//  - f1a: keep round-7's 128-node x 2-colhalf blocks (6.1 blocks/CU) but fix
//    the round-7 regression: chalf = t>>7 made the weight pointer THREAD-
//    dependent -> compiler dropped s_load weights (SGPR 112->32) and used
//    per-lane VMEM loads (215 us). readfirstlane(t>>7) is wave-uniform by
//    construction -> restores scalar weight path + keeps the occupancy gain.
//    Inner unroll back to 4 (round-3 proven SGPR pressure).
//  - Everything else identical to round 7 (aggs' float4 gather kept: rest of
//    pipeline improved ~20 us vs round 5).
// ---------------------------------------------------------------------------

#define BK_SHIFT 8
#define BK_SIZE 256

__device__ __forceinline__ void acc4(float4& a, float4 v) {
    a.x += v.x; a.y += v.y; a.z += v.z; a.w += v.w;
}

__global__ void hist_kernel(const int* __restrict__ dst, int* __restrict__ cnt, int E) {
    int e = blockIdx.x * 256 + threadIdx.x;
    if (e < E) atomicAdd(&cnt[dst[e]], 1);
}

// ---- multi-block exclusive scan over cnt[N] -> off[N+1], invc[N] ----
__global__ void scan_reduce_kernel(const int* __restrict__ cnt, int* __restrict__ bsum, int n) {
    int t = threadIdx.x;
    int i = blockIdx.x * 256 + t;
    int v = (i < n) ? cnt[i] : 0;
#pragma unroll
    for (int s = 32; s > 0; s >>= 1) v += __shfl_down(v, s, 64);
    __shared__ int ws[4];
    if ((t & 63) == 0) ws[t >> 6] = v;
    __syncthreads();
    if (t == 0) bsum[blockIdx.x] = ws[0] + ws[1] + ws[2] + ws[3];
}

__global__ void scan_mid_kernel(const int* __restrict__ bsum, int* __restrict__ bbase, int nb) {
    __shared__ int sd[256];
    __shared__ int carry;
    int t = threadIdx.x;
    if (t == 0) carry = 0;
    __syncthreads();
    for (int base = 0; base < nb; base += 256) {
        int v = (base + t < nb) ? bsum[base + t] : 0;
        sd[t] = v;
        __syncthreads();
        for (int d = 1; d < 256; d <<= 1) {
            int x = (t >= d) ? sd[t - d] : 0;
            __syncthreads();
            sd[t] += x;
            __syncthreads();
        }
        if (base + t < nb) bbase[base + t] = carry + sd[t] - v;
        __syncthreads();
        if (t == 0) carry += sd[255];
        __syncthreads();
    }
}

__global__ void scan_final_kernel(const int* __restrict__ cnt, const int* __restrict__ bbase,
                                  int* __restrict__ off, float* __restrict__ invc, int n) {
    __shared__ int sd[256];
    int t = threadIdx.x;
    int i = blockIdx.x * 256 + t;
    int v = (i < n) ? cnt[i] : 0;
    sd[t] = v;
    __syncthreads();
    for (int d = 1; d < 256; d <<= 1) {
        int x = (t >= d) ? sd[t - d] : 0;
        __syncthreads();
        sd[t] += x;
        __syncthreads();
    }
    if (i < n) {
        off[i + 1] = bbase[blockIdx.x] + sd[t];
        invc[i] = 1.0f / fmaxf((float)v, 1.0f);
    }
    if (i == 0) off[0] = 0;
}

__global__ void init_gcur_kernel(const int* __restrict__ off, int* __restrict__ gcur, int nb, int n) {
    int b = blockIdx.x * 256 + threadIdx.x;
    if (b < nb) gcur[b] = off[b * BK_SIZE];
}

// ---- phase A: bin edges into buckets of BK_SIZE dst nodes ----
__global__ __launch_bounds__(256) void bucketA_kernel(const int* __restrict__ src,
    const int* __restrict__ dst, int* __restrict__ gcur,
    uint2* __restrict__ pairs, int E, int nb)
{
    __shared__ int lcnt[256];
    __shared__ int lbase[256];
    int t = threadIdx.x;
    int cbase = blockIdx.x * 4096;
    lcnt[t] = 0;
    __syncthreads();
#pragma unroll
    for (int r = 0; r < 16; ++r) {
        int e = cbase + r * 256 + t;
        if (e < E) atomicAdd(&lcnt[dst[e] >> BK_SHIFT], 1);
    }
    __syncthreads();
    if (t < nb && lcnt[t] > 0) lbase[t] = atomicAdd(&gcur[t], lcnt[t]);
    lcnt[t] = 0;
    __syncthreads();
#pragma unroll
    for (int r = 0; r < 16; ++r) {
        int e = cbase + r * 256 + t;
        if (e < E) {
            int d = dst[e];
            int bk = d >> BK_SHIFT;
            int pos = lbase[bk] + atomicAdd(&lcnt[bk], 1);
            pairs[pos] = make_uint2((unsigned)src[e], (unsigned)d);
        }
    }
}

// ---- phase B: per-bucket LDS-cursor final placement ----
__global__ __launch_bounds__(256) void bucketB_kernel(const uint2* __restrict__ pairs,
    const int* __restrict__ off, int* __restrict__ csr, int n)
{
    __shared__ int lcur[BK_SIZE];
    int t = threadIdx.x;
    int b = blockIdx.x;
    int d0 = b * BK_SIZE;
    int dlim = min(BK_SIZE, n - d0);
    if (t < dlim) lcur[t] = off[d0 + t];
    __syncthreads();
    int start = off[d0];
    int end = off[min(d0 + BK_SIZE, n)];
    for (int i = start + t; i < end; i += 256) {
        uint2 p = pairs[i];
        int pos = atomicAdd(&lcur[p.y & (BK_SIZE - 1)], 1);
        csr[pos] = (int)p.x;
    }
}

// ---------------------------------------------------------------------------
// f1a: des[N,768] @ W_des[768,32], split-K x4 (192 k each).
// 128 nodes/block, 256 threads = (node 0..127) x (col-half via rfl), staged
// 32-k chunks in LDS (16.5 KB; grid (ceil(N/128),4) -> ~6 blocks/CU).
// chalf = readfirstlane(t>>7): wave-uniform SGPR -> weight rows stay s_load
// (round-7 lesson: thread-dependent weight base drops to VMEM, 2.2x slower).
// Partials feature-major: part[(split*32 + chalf*16 + c)*N + node].
// ---------------------------------------------------------------------------
__global__ __launch_bounds__(256) void f1a_kernel(const float* __restrict__ des,
    const float* __restrict__ W, float* __restrict__ part, int n)
{
    __shared__ float sX[32 * 129];
    int t = threadIdx.x;
    int nbase = blockIdx.x * 128;
    int nl = t & 127;                                        // node within block
    int chalf = __builtin_amdgcn_readfirstlane(t >> 7);      // SGPR, wave-uniform
    int node = nbase + nl;
    int kb0 = blockIdx.y * 192;
    int c0 = chalf * 16;                                     // SGPR
    float acc[16];
#pragma unroll
    for (int c = 0; c < 16; ++c) acc[c] = 0.f;

    for (int kc = 0; kc < 192; kc += 32) {
        __syncthreads();
#pragma unroll
        for (int r = 0; r < 4; ++r) {
            int i = r * 256 + t;          // 0..1023 float4 slots
            int k4 = i & 7, nn = i >> 3;  // 8 float4 along k, 128 nodes
            int gn = nbase + nn;
            float4 v = make_float4(0.f, 0.f, 0.f, 0.f);
            if (gn < n)
                v = *reinterpret_cast<const float4*>(des + (size_t)gn * 768 + kb0 + kc + k4 * 4);
            sX[(k4 * 4 + 0) * 129 + nn] = v.x;
            sX[(k4 * 4 + 1) * 129 + nn] = v.y;
            sX[(k4 * 4 + 2) * 129 + nn] = v.z;
            sX[(k4 * 4 + 3) * 129 + nn] = v.w;
        }
        __syncthreads();
        const float* wbase = W + (size_t)(kb0 + kc) * 32 + c0;   // scalar base
#pragma unroll 4
        for (int k = 0; k < 32; ++k) {
            float x = sX[k * 129 + nl];
            const float* wr = wbase + k * 32;   // wave-uniform -> s_load
#pragma unroll
            for (int c = 0; c < 16; ++c) acc[c] = fmaf(x, wr[c], acc[c]);
        }
    }
    if (node < n) {
        float* po = part + (size_t)(blockIdx.y * 32 + c0) * n + node;
#pragma unroll
        for (int c = 0; c < 16; ++c) po[(size_t)c * n] = acc[c];   // coalesced
    }
}

// f1c: sum 4 transposed partial slabs + bias + leaky -> X^T rows 0..31 (P0)
__global__ __launch_bounds__(256) void f1c_kernel(const float* __restrict__ part,
    const float* __restrict__ b, float* __restrict__ XT, int n)
{
    int node = blockIdx.x * 256 + threadIdx.x;
    if (node >= n) return;
#pragma unroll 8
    for (int c = 0; c < 32; ++c) {
        float v = b[c];
#pragma unroll
        for (int s = 0; s < 4; ++s) v += part[(size_t)(s * 32 + c) * n + node];
        v = v > 0.f ? v : 0.01f * v;
        XT[(size_t)c * n + node] = v;
    }
}

// f1b: num/cat linears -> X^T rows 32..115 (feature-major, coalesced stores)
__global__ __launch_bounds__(256) void f1b_kernel(const float* __restrict__ nump,
    const float* __restrict__ catp,
    const float* __restrict__ Wn, const float* __restrict__ bn,
    const float* __restrict__ Wc, const float* __restrict__ bc,
    float* __restrict__ XT, int n)
{
    int node = blockIdx.x * 256 + threadIdx.x;
    if (node >= n) return;
    float4 nv = *reinterpret_cast<const float4*>(nump + (size_t)node * 4);
    float c0 = catp[(size_t)node * 3];
    float c1 = catp[(size_t)node * 3 + 1];
    float c2 = catp[(size_t)node * 3 + 2];
#pragma unroll 6
    for (int c = 0; c < 42; ++c) {
        float vn = bn[c] + nv.x * Wn[c] + nv.y * Wn[42 + c] + nv.z * Wn[84 + c] + nv.w * Wn[126 + c];
        vn = vn > 0.f ? vn : 0.01f * vn;
        XT[(size_t)(32 + c) * n + node] = vn;
        float vc = bc[c] + c0 * Wc[c] + c1 * Wc[42 + c] + c2 * Wc[84 + c];
        vc = vc > 0.f ? vc : 0.01f * vc;
        XT[(size_t)(74 + c) * n + node] = vc;
    }
}

// ---------------------------------------------------------------------------
// gemm_t: transposed-input node-per-lane GEMM. X is feature-major [K][N]:
// lane load X[k*N+node] is perfectly coalesced -> NO LDS, NO barriers.
// 8 column splits of 16 (grid (nbn,8)).
// MODE 0: WA[K][128] cols cs*16.  MODE 1: cs<4 -> WA[K][64], else WB[K][64].
// ACT: 0 none, 1 relu, 2 leaky.  BIASM: 1 full bias[c0+c]; 2 only cs>=4.
// OUT: 0 transposed dword stores; 1 node-major float4; 3 fused head
//      (leaky(+bias) @ W_o2[128,2] -> atomicAdd, bias2 added by cs==0).
// ---------------------------------------------------------------------------
template<int K, int MODE, int ACT, int BIASM, int OUT>
__global__ __launch_bounds__(256) void gemm_t_kernel(
    const float* __restrict__ X,
    const float* __restrict__ WA, const float* __restrict__ WB,
    const float* __restrict__ bias, const float* __restrict__ bias2,
    float* __restrict__ Y, int n)
{
    int t = threadIdx.x;
    int node = blockIdx.x * 256 + t;
    if (node >= n) return;                     // no barriers -> safe
    int cs = blockIdx.y;
    int c0 = cs * 16;
    float acc[16];
#pragma unroll
    for (int c = 0; c < 16; ++c) acc[c] = 0.f;

    const float* xp = X + node;
    const float* wr0;
    if (MODE == 0)      wr0 = WA + c0;
    else                wr0 = (cs < 4) ? (WA + c0) : (WB + (c0 - 64));
    const int wstride = (MODE == 0) ? 128 : 64;

#pragma unroll 8
    for (int k = 0; k < K; ++k) {
        float x = xp[(size_t)k * n];           // coalesced dword load
        const float* wr = wr0 + (size_t)k * wstride;  // wave-uniform -> s_load
#pragma unroll
        for (int c = 0; c < 16; ++c) acc[c] = fmaf(x, wr[c], acc[c]);
    }

    if (OUT == 3) {
        // fused head: leaky(acc + b_o1) @ W_o2[128,2] partial -> atomicAdd
        float o0 = (cs == 0) ? bias2[0] : 0.f;
        float o1 = (cs == 0) ? bias2[1] : 0.f;
#pragma unroll
        for (int c = 0; c < 16; ++c) {
            float v = acc[c] + bias[c0 + c];
            v = v > 0.f ? v : 0.01f * v;
            o0 = fmaf(v, WB[(c0 + c) * 2],     o0);
            o1 = fmaf(v, WB[(c0 + c) * 2 + 1], o1);
        }
        atomicAdd(&Y[(size_t)node * 2],     o0);
        atomicAdd(&Y[(size_t)node * 2 + 1], o1);
        return;
    }

#pragma unroll
    for (int c = 0; c < 16; ++c) {
        float v = acc[c];
        if (BIASM == 1) v += bias[c0 + c];
        if (BIASM == 2) { if (cs >= 4) v += bias[c0 - 64 + c]; }
        if (ACT == 1) v = fmaxf(v, 0.f);
        else if (ACT == 2) v = v > 0.f ? v : 0.01f * v;
        acc[c] = v;
    }
    if (OUT == 0) {
#pragma unroll
        for (int c = 0; c < 16; ++c)
            Y[(size_t)(c0 + c) * n + node] = acc[c];   // coalesced
    } else {
        float* yp = Y + (size_t)node * 128 + c0;
#pragma unroll
        for (int c4 = 0; c4 < 4; ++c4)
            *reinterpret_cast<float4*>(yp + c4 * 4) =
                make_float4(acc[c4 * 4], acc[c4 * 4 + 1], acc[c4 * 4 + 2], acc[c4 * 4 + 3]);
    }
}

// ---------------------------------------------------------------------------
// gemm_sage_b: node-major input [N,128] (from agg_b), staged (round-5 form).
// K=128 split 64/64 across WA[64][128]/WB[64][128]. 8 column splits of 16,
// 16-k chunks (LDS 16.5 KB, stride 258). Output relu, feature-major stores.
// ---------------------------------------------------------------------------
__global__ __launch_bounds__(256) void gemm_sage_b_kernel(
    const float* __restrict__ X,
    const float* __restrict__ WA, const float* __restrict__ WB,
    const float* __restrict__ bias,
    float* __restrict__ Y, int n)
{
    __shared__ float sX[16 * 258];
    int t = threadIdx.x;
    int nbase = blockIdx.x * 256;
    int node = nbase + t;
    int cs = blockIdx.y;
    int c0 = cs * 16;
    float acc[16];
#pragma unroll
    for (int c = 0; c < 16; ++c) acc[c] = 0.f;

    for (int ch = 0; ch < 8; ++ch) {
        int kb = ch * 16;
        __syncthreads();
#pragma unroll
        for (int r = 0; r < 4; ++r) {
            int i = r * 256 + t;
            int k4 = i & 3, nn = i >> 2;
            int gn = nbase + nn;
            float4 v = make_float4(0.f, 0.f, 0.f, 0.f);
            if (gn < n)
                v = *reinterpret_cast<const float4*>(X + (size_t)gn * 128 + kb + k4 * 4);
            sX[(k4 * 4 + 0) * 258 + nn] = v.x;
            sX[(k4 * 4 + 1) * 258 + nn] = v.y;
            sX[(k4 * 4 + 2) * 258 + nn] = v.z;
            sX[(k4 * 4 + 3) * 258 + nn] = v.w;
        }
        __syncthreads();
#pragma unroll 4
        for (int k = 0; k < 16; ++k) {
            float x = sX[k * 258 + t];
            int kk = kb + k;
            const float* wr = (kk < 64) ? (WA + (size_t)kk * 128 + c0)
                                        : (WB + (size_t)(kk - 64) * 128 + c0);
#pragma unroll
            for (int c = 0; c < 16; ++c) acc[c] = fmaf(x, wr[c], acc[c]);
        }
    }

    if (node >= n) return;
#pragma unroll
    for (int c = 0; c < 16; ++c) {
        float v = fmaxf(acc[c] + bias[c0 + c], 0.f);
        Y[(size_t)(c0 + c) * n + node] = v;    // coalesced feature-major
    }
}

// ---------------------------------------------------------------------------
// agg_a: H[dst] = relu(mean_agg(Y[:,0:64]) + Y[dst,64:128]).
// Wave per node; lane = (edge slot e4 = l>>4) x (feature quad fq = l&15).
// Each gather instr: 4 rows x 256 B = 1 KB; 4-group batch -> 16 rows in
// flight. 2-step shfl reduce across e4; lanes 0..15 write float4.
// ---------------------------------------------------------------------------
__global__ __launch_bounds__(256) void agg_a_kernel(const float* __restrict__ Y,
    const int* __restrict__ off, const int* __restrict__ csr,
    const float* __restrict__ invc, float* __restrict__ H, int n)
{
    int wid = (blockIdx.x * 256 + threadIdx.x) >> 6;
    int l = threadIdx.x & 63;
    if (wid >= n) return;
    int e4 = l >> 4, fq = l & 15;
    int b = off[wid], e = off[wid + 1];
    int deg = e - b;
    int nfull = deg >> 2;           // 4-edge groups
    float4 acc = make_float4(0.f, 0.f, 0.f, 0.f);
    int i = b + e4;
    int g = 0;
    for (; g + 4 <= nfull; g += 4, i += 16) {
        int i0 = csr[i], i1 = csr[i + 4], i2 = csr[i + 8], i3 = csr[i + 12];
        float4 v0 = *reinterpret_cast<const float4*>(Y + (size_t)i0 * 128 + fq * 4);
        float4 v1 = *reinterpret_cast<const float4*>(Y + (size_t)i1 * 128 + fq * 4);
        float4 v2 = *reinterpret_cast<const float4*>(Y + (size_t)i2 * 128 + fq * 4);
        float4 v3 = *reinterpret_cast<const float4*>(Y + (size_t)i3 * 128 + fq * 4);
        acc4(acc, v0); acc4(acc, v1); acc4(acc, v2); acc4(acc, v3);
    }
    for (; g < nfull; ++g, i += 4) {
        int i0 = csr[i];
        acc4(acc, *reinterpret_cast<const float4*>(Y + (size_t)i0 * 128 + fq * 4));
    }
    int rem = deg & 3;
    if (e4 < rem) {
        int i0 = csr[b + (nfull << 2) + e4];
        acc4(acc, *reinterpret_cast<const float4*>(Y + (size_t)i0 * 128 + fq * 4));
    }
    // reduce across e4 groups (lanes l, l+16, l+32, l+48 -> lane l<16)
    acc.x += __shfl_down(acc.x, 32, 64); acc.y += __shfl_down(acc.y, 32, 64);
    acc.z += __shfl_down(acc.z, 32, 64); acc.w += __shfl_down(acc.w, 32, 64);
    acc.x += __shfl_down(acc.x, 16, 64); acc.y += __shfl_down(acc.y, 16, 64);
    acc.z += __shfl_down(acc.z, 16, 64); acc.w += __shfl_down(acc.w, 16, 64);
    if (e4 == 0) {
        float ic = invc[wid];
        float4 root = *reinterpret_cast<const float4*>(Y + (size_t)wid * 128 + 64 + fq * 4);
        float4 o;
        o.x = fmaxf(acc.x * ic + root.x, 0.f);
        o.y = fmaxf(acc.y * ic + root.y, 0.f);
        o.z = fmaxf(acc.z * ic + root.z, 0.f);
        o.w = fmaxf(acc.w * ic + root.w, 0.f);
        *reinterpret_cast<float4*>(H + (size_t)wid * 64 + fq * 4) = o;
    }
}

// agg_b: Z[dst,0:64] = mean_agg(H), Z[dst,64:128] = H[dst]. Same scheme,
// H rows are 64 floats.
__global__ __launch_bounds__(256) void agg_b_kernel(const float* __restrict__ H,
    const int* __restrict__ off, const int* __restrict__ csr,
    const float* __restrict__ invc, float* __restrict__ Z, int n)
{
    int wid = (blockIdx.x * 256 + threadIdx.x) >> 6;
    int l = threadIdx.x & 63;
    if (wid >= n) return;
    int e4 = l >> 4, fq = l & 15;
    int b = off[wid], e = off[wid + 1];
    int deg = e - b;
    int nfull = deg >> 2;
    float4 acc = make_float4(0.f, 0.f, 0.f, 0.f);
    int i = b + e4;
    int g = 0;
    for (; g + 4 <= nfull; g += 4, i += 16) {
        int i0 = csr[i], i1 = csr[i + 4], i2 = csr[i + 8], i3 = csr[i + 12];
        float4 v0 = *reinterpret_cast<const float4*>(H + (size_t)i0 * 64 + fq * 4);
        float4 v1 = *reinterpret_cast<const float4*>(H + (size_t)i1 * 64 + fq * 4);
        float4 v2 = *reinterpret_cast<const float4*>(H + (size_t)i2 * 64 + fq * 4);
        float4 v3 = *reinterpret_cast<const float4*>(H + (size_t)i3 * 64 + fq * 4);
        acc4(acc, v0); acc4(acc, v1); acc4(acc, v2); acc4(acc, v3);
    }
    for (; g < nfull; ++g, i += 4) {
        int i0 = csr[i];
        acc4(acc, *reinterpret_cast<const float4*>(H + (size_t)i0 * 64 + fq * 4));
    }
    int rem = deg & 3;
    if (e4 < rem) {
        int i0 = csr[b + (nfull << 2) + e4];
        acc4(acc, *reinterpret_cast<const float4*>(H + (size_t)i0 * 64 + fq * 4));
    }
    acc.x += __shfl_down(acc.x, 32, 64); acc.y += __shfl_down(acc.y, 32, 64);
    acc.z += __shfl_down(acc.z, 32, 64); acc.w += __shfl_down(acc.w, 32, 64);
    acc.x += __shfl_down(acc.x, 16, 64); acc.y += __shfl_down(acc.y, 16, 64);
    acc.z += __shfl_down(acc.z, 16, 64); acc.w += __shfl_down(acc.w, 16, 64);
    if (e4 == 0) {
        float ic = invc[wid];
        float4 root = *reinterpret_cast<const float4*>(H + (size_t)wid * 64 + fq * 4);
        float4 m;
        m.x = acc.x * ic; m.y = acc.y * ic; m.z = acc.z * ic; m.w = acc.w * ic;
        *reinterpret_cast<float4*>(Z + (size_t)wid * 128 + fq * 4) = m;
        *reinterpret_cast<float4*>(Z + (size_t)wid * 128 + 64 + fq * 4) = root;
    }
}

extern "C" void kernel_launch(void* const* d_in, const int* in_sizes, int n_in,
                              void* d_out, int out_size, void* d_ws, size_t ws_size,
                              hipStream_t stream)
{
    const float* des   = (const float*)d_in[0];
    const float* nump  = (const float*)d_in[2];
    const float* catp  = (const float*)d_in[3];
    const int*   ei    = (const int*)d_in[4];
    const float* W_des = (const float*)d_in[5];  const float* b_des = (const float*)d_in[6];
    const float* W_num = (const float*)d_in[7];  const float* b_num = (const float*)d_in[8];
    const float* W_cat = (const float*)d_in[9];  const float* b_cat = (const float*)d_in[10];
    const float* W_in  = (const float*)d_in[11]; const float* b_in  = (const float*)d_in[12];
    const float* s1a_Wl = (const float*)d_in[13]; const float* s1a_bl = (const float*)d_in[14];
    const float* s1a_Wr = (const float*)d_in[15];
    const float* s1b_Wl = (const float*)d_in[16]; const float* s1b_bl = (const float*)d_in[17];
    const float* s1b_Wr = (const float*)d_in[18];
    const float* s2a_Wl = (const float*)d_in[19]; const float* s2a_bl = (const float*)d_in[20];
    const float* s2a_Wr = (const float*)d_in[21];
    const float* s2b_Wl = (const float*)d_in[22]; const float* s2b_bl = (const float*)d_in[23];
    const float* s2b_Wr = (const float*)d_in[24];
    const float* W_o1  = (const float*)d_in[25]; const float* b_o1 = (const float*)d_in[26];
    const float* W_o2  = (const float*)d_in[27]; const float* b_o2 = (const float*)d_in[28];
    float* out = (float*)d_out;

    int N = in_sizes[0] / 768;
    int E = in_sizes[4] / 2;
    const int* srcp = ei;
    const int* dstp = ei + E;
    int NB = (N + BK_SIZE - 1) >> BK_SHIFT;       // dst buckets
    int NBLK = (N + 255) / 256;                   // scan blocks

    float* P0 = (float*)d_ws;
    float* P1 = P0 + (size_t)128 * N;
    float* P2 = P1 + (size_t)128 * N;   // pairs during CSR
    int* cnt   = (int*)(P2 + (size_t)128 * N);
    int* off   = cnt + N;
    float* invc = (float*)(off + (N + 1));
    int* csr   = (int*)(invc + N);
    int* bsum  = csr + E;
    int* bbase = bsum + NBLK;
    int* gcur  = bbase + NBLK;
    uint2* pairs = (uint2*)P2;

    // --- CSR build ---
    hipMemsetAsync(cnt, 0, (size_t)N * sizeof(int), stream);
    hipMemsetAsync(out, 0, (size_t)N * 2 * sizeof(float), stream);  // fused-head atomics
    hist_kernel<<<(E + 255) / 256, 256, 0, stream>>>(dstp, cnt, E);
    scan_reduce_kernel<<<NBLK, 256, 0, stream>>>(cnt, bsum, N);
    scan_mid_kernel<<<1, 256, 0, stream>>>(bsum, bbase, NBLK);
    scan_final_kernel<<<NBLK, 256, 0, stream>>>(cnt, bbase, off, invc, N);
    init_gcur_kernel<<<(NB + 255) / 256, 256, 0, stream>>>(off, gcur, NB, N);
    bucketA_kernel<<<(E + 4095) / 4096, 256, 0, stream>>>(srcp, dstp, gcur, pairs, E, NB);
    bucketB_kernel<<<NB, 256, 0, stream>>>(pairs, off, csr, N);

    int nbn = (N + 255) / 256;
    int nbn128 = (N + 127) / 128;
    dim3 g8(nbn, 8);
    int nbw = (N + 3) / 4;

    // --- Front MLP:  X^T in P0 (rows 0..115) ---
    f1a_kernel<<<dim3(nbn128, 4), 256, 0, stream>>>(des, W_des, P1, N);  // 4 slabs in P1
    f1b_kernel<<<nbn, 256, 0, stream>>>(nump, catp, W_num, b_num, W_cat, b_cat, P0, N);
    f1c_kernel<<<nbn, 256, 0, stream>>>(P1, b_des, P0, N);
    gemm_t_kernel<116, 0, 2, 1, 0><<<g8, 256, 0, stream>>>(P0, W_in, nullptr, b_in, nullptr, P1, N);

    // --- SAGE block 1 ---
    gemm_t_kernel<128, 1, 0, 2, 1><<<g8, 256, 0, stream>>>(P1, s1a_Wl, s1a_Wr, s1a_bl, nullptr, P2, N);
    agg_a_kernel<<<nbw, 256, 0, stream>>>(P2, off, csr, invc, P0, N);
    agg_b_kernel<<<nbw, 256, 0, stream>>>(P0, off, csr, invc, P1, N);
    gemm_sage_b_kernel<<<g8, 256, 0, stream>>>(P1, s1b_Wl, s1b_Wr, s1b_bl, P2, N);

    // --- SAGE block 2 ---
    gemm_t_kernel<128, 1, 0, 2, 1><<<g8, 256, 0, stream>>>(P2, s2a_Wl, s2a_Wr, s2a_bl, nullptr, P0, N);
    agg_a_kernel<<<nbw, 256, 0, stream>>>(P0, off, csr, invc, P1, N);
    agg_b_kernel<<<nbw, 256, 0, stream>>>(P1, off, csr, invc, P0, N);
    gemm_sage_b_kernel<<<g8, 256, 0, stream>>>(P0, s2b_Wl, s2b_Wr, s2b_bl, P1, N);

    // --- Head: leaky(X3^T @ W_o1 + b_o1) @ W_o2 + b_o2 (fused, atomics) ---
    gemm_t_kernel<128, 0, 3, 1, 3><<<g8, 256, 0, stream>>>(P1, W_o1, W_o2, b_o1, b_o2, out, N);
}